// Round 8
// baseline (2272.642 us; speedup 1.0000x reference)
//
#include <hip/hip_runtime.h>

// ---------------------------------------------------------------------------
// Recurrent ReLU net on MI355X — parity-only dataflow, RING=3, v26.
//   v25 (1.286 ms) was neutral vs v23 (1.284 ms): store-ack drain already
//   hidden. Remaining wall per the arithmetic: EXCHANGE BANDWIDTH.
//   Every WG reads its full 64 KB plane-h via sc1 -> device-wide 16 MB/step,
//   2 MB per XCD fabric port ~ 5000 cy at ~417 B/cy — matches the 6030 cy
//   step. Volume scales ONLY as 2048/CW (plane count cancels).
//   v26: CW=64, NWG=128 — HALVES the exchange (8 MB/step, 1 MB/XCD).
//   Payload loads per wave are UNCHANGED (same 8 fragments); each WG now
//   computes 64 output cols from them. Fitting 2x W per WG (the hard part):
//     - hi nt0,1 in LDS (128 KB, same layout); hi nt2,3 in VGPRs (64);
//       lo[8][4] in VGPRs (128); bh01 streamed per-fragment (no preload).
//     - SINGLE acc per nt: lo folded into acch by scaling A instead of acc:
//       A_lo = h * 2^-12 (exact pow2 in fp16; subnormal flush for h<0.25
//       contributes <=~1e-4 — payload-fp16 error still dominates) with
//       blo stored *4096 as before -> product == h*res exactly.
//     - sp single-buffer 20 KB (safe: both barriers bracket read/write);
//       512-output epilogue, 1 col-pair per thread, 2 KB contiguous store.
//     - W_in/b_in/x loaded in epilogue on micro==0 steps (not persisted).
//   Protocol byte-identical: parity+RING=3, LATE joint drain, both barriers,
//   sc1 only, conditional reload sleep. Lessons: v20/v22/v24 catalogued.
//   OccupancyPercent will read ~12% (128 WGs on 256 CUs) — expected;
//   compute is not the constraint, fabric BW is.
// ---------------------------------------------------------------------------

#define N_DIM   2048
#define B_DIM   64
#define T_DIM   128
#define NSENS   256
#define NOUT    128
#define NSTEP   512

#define NWG     128
#define THREADS 512
#define CW      64
#define RING    3
#define SLOT_F16 (B_DIM * N_DIM)       // 131072 f16 = 256 KB per slot
#define SP_S    20
#define SP_ROWS 512
#define LDS_W_F16 (32 * N_DIM)         // hi nt0,1: 65536 f16 = 128 KB
#define SMEM_MAIN (LDS_W_F16 * 2 + SP_ROWS * SP_S * 2)   // 151,552 B

typedef _Float16 f16x8 __attribute__((ext_vector_type(8)));
typedef _Float16 f16x4 __attribute__((ext_vector_type(4)));
typedef float    f32x4 __attribute__((ext_vector_type(4)));
typedef unsigned long long u64;
typedef unsigned short u16;

#define SIGN_M32 0x80008000u
#define SIGN_M64 0x8000800080008000ULL

union V16 { uint4 q; u64 u[2]; };

// ---------------- setup kernels ----------------

// slot 0 holds h_0 = -0 (sign SET, valid for even step 0).
// slot 1 first read at s=1 (expect CLEAR) -> init SET (invalid).
// slot 2 first read at s=2 (expect SET)  -> init CLEAR (invalid).
__global__ void k_init(uint4* __restrict__ ring, int* __restrict__ inv_sens,
                       int* __restrict__ inv_out, u64* __restrict__ flags) {
    const int i = blockIdx.x * blockDim.x + threadIdx.x;   // 49152 threads
    const int slot = i / (SLOT_F16 / 8);
    if (slot < RING) {
        const unsigned pat = (slot == 0 || (slot & 1)) ? SIGN_M32 : 0u;
        ring[i] = make_uint4(pat, pat, pat, pat);
    }
    if (i < N_DIM) { inv_sens[i] = -1; inv_out[i] = -1; }
    if (i < 64) flags[i] = 0ull;       // unused by v26 main; kept harmless
}

__global__ void k_inv_scatter(int* inv_sens, int* inv_out,
                              const int* sidx, const int* oidx) {
    int i = threadIdx.x;
    if (i < NSENS) inv_sens[sidx[i]] = i;
    if (i < NOUT)  inv_out[oidx[i]] = i;
}

// ---------------- main persistent kernel ----------------
// slot layout: fp16 MFMA A-fragment order (UNCHANGED).
//   elem (b, j): f16 offset = ((b>>4)*64 + (j>>5))*512 + (((j>>3)&3)*16 + (b&15))*8 + (j&7)
// Fragment (pl, kt) = 1 KB. Producer of kt: WG (pl, cg = kt>>1) (CW=64 ->
// each WG produces k-tiles 2cg, 2cg+1 = 2 KB contiguous).
// Wave A-load: ONE dense dwordx4 sc1 per fragment (16 B/lane contiguous),
// k-slab per wave unchanged (k-tiles wv*8..wv*8+7).
// Store map: thread d owns fragment-pair dword d (2 KB contiguous per WG):
//   r = d&255, frag = d>>8, b = (r>>2)&15, jl = frag*32+((r>>6)&3)*8+(r&3)*2

__global__ __launch_bounds__(THREADS, 1)
void rnn_main(const float* __restrict__ W_rec, const float* __restrict__ inputs,
              const float* __restrict__ W_in, const float* __restrict__ b_in,
              const int* __restrict__ inv_sens, const int* __restrict__ inv_out,
              _Float16* __restrict__ ring, _Float16* __restrict__ hc,
              u16* __restrict__ flags /* unused in v26 */)
{
    extern __shared__ _Float16 smem[];
    _Float16* w_hi = smem;                  // [128 blocks][512] hi nt0,1
    _Float16* sp   = smem + LDS_W_F16;      // [512][SP_S] single buffer

    const int tid   = threadIdx.x;
    const int wg    = blockIdx.x;
    const int pl    = wg & 3;        // plane: batch rows pl*16..+15
    const int cg    = wg >> 2;       // col group 0..31: cols cg*64..+63
    const int jbase = cg * CW;

    const int lane = tid & 63;
    const int wv   = tid >> 6;       // wave = K-slab (k-tiles wv*8..wv*8+7)
    const int lrow = lane & 15;
    const int quad = lane >> 4;
    (void)flags;

    // ---- stage W: hi nt0,1 -> LDS; hi nt2,3 -> VGPR; lo (x4096) -> VGPR ----
    f16x8 blo[8][4];
    f16x8 bh23[8][2];
#pragma unroll
    for (int nt = 0; nt < 4; ++nt) {
        const float* wr = W_rec + (size_t)(jbase + nt * 16 + lrow) * N_DIM
                        + wv * 256 + quad * 8;
#pragma unroll
        for (int ks = 0; ks < 8; ++ks) {
            const float4 wa = ((const float4*)(wr + ks * 32))[0];
            const float4 wb = ((const float4*)(wr + ks * 32))[1];
            const float w8[8] = {wa.x, wa.y, wa.z, wa.w, wb.x, wb.y, wb.z, wb.w};
            f16x8 hi8;
#pragma unroll
            for (int e = 0; e < 8; ++e) {
                const _Float16 hi = (_Float16)w8[e];
                hi8[e] = hi;
                blo[ks][nt][e] = (_Float16)((w8[e] - (float)hi) * 4096.0f);
            }
            if (nt < 2)
                *(f16x8*)(w_hi + ((((wv * 8 + ks) * 2 + nt)) << 9) + lane * 8) = hi8;
            else
                bh23[ks][nt - 2] = hi8;
        }
    }

    // ---- epilogue constants: thread d owns fragment-pair dword d ----
    const int d    = tid;
    const int r    = d & 255;
    const int frag = d >> 8;
    const int ebl  = (r >> 2) & 15;                       // batch row 0..15
    const int jl   = frag * 32 + ((r >> 6) & 3) * 8 + (r & 3) * 2; // col 0..62
    const int ep_b = pl * 16 + ebl;                       // global batch row
    const int ej   = jbase + jl;                          // global col, even
    const int ep_sA = inv_sens[ej], ep_sB = inv_sens[ej + 1];
    const int ep_uA = inv_out[ej],  ep_uB = inv_out[ej + 1];
    // 2 KB contiguous per WG: f16 offset = (pl*64 + 2cg)*512 + d*2
    const int ep_off = ((pl * 64 + 2 * cg) << 9) + (d << 1);
    __syncthreads();

    int slot_r = 0, slot_w = 1;

    for (int step = 0; step < NSTEP; ++step) {
        const int t = step >> 2, micro = step & 3;
        const bool expSet = (step & 1) == 0;     // parity of h_step
        const _Float16* __restrict__ hcur = ring + (size_t)slot_r * SLOT_F16;
        _Float16* __restrict__       hnxt = ring + (size_t)slot_w * SLOT_F16;

        // ---- issue 8 payload fragments (no drain yet) — UNCHANGED ----
        const _Float16* hb = hcur + ((pl * 64 + wv * 8) << 9) + lane * 8;
        V16 a[8];
        asm volatile(
            "global_load_dwordx4 %0, %8, off sc1\n\t"
            "global_load_dwordx4 %1, %9, off sc1\n\t"
            "global_load_dwordx4 %2, %10, off sc1\n\t"
            "global_load_dwordx4 %3, %11, off sc1\n\t"
            "global_load_dwordx4 %4, %12, off sc1\n\t"
            "global_load_dwordx4 %5, %13, off sc1\n\t"
            "global_load_dwordx4 %6, %14, off sc1\n\t"
            "global_load_dwordx4 %7, %15, off sc1"
            : "=v"(a[0].q), "=v"(a[1].q), "=v"(a[2].q), "=v"(a[3].q),
              "=v"(a[4].q), "=v"(a[5].q), "=v"(a[6].q), "=v"(a[7].q)
            : "v"(hb),        "v"(hb + 512),  "v"(hb + 1024), "v"(hb + 1536),
              "v"(hb + 2048), "v"(hb + 2560), "v"(hb + 3072), "v"(hb + 3584)
            : "memory");

        f32x4 acc[4];
#pragma unroll
        for (int nt = 0; nt < 4; ++nt) acc[nt] = (f32x4){0.f, 0.f, 0.f, 0.f};

        // ---- LATE joint drain, then parity-driven consume ----
        asm volatile("s_waitcnt vmcnt(0)" ::: "memory");
        __builtin_amdgcn_sched_barrier(0);   // rule #18

        unsigned live = 0xFFu;
        int rounds = 0;
        while (live) {
#pragma unroll
            for (int f = 0; f < 8; ++f) if (live & (1u << f)) {
                const u64 band = a[f].u[0] & a[f].u[1];
                const u64 bor  = a[f].u[0] | a[f].u[1];
                const bool ok = expSet ? ((band & SIGN_M64) == SIGN_M64)
                                       : ((bor  & SIGN_M64) == 0);
                if (__all((int)ok)) {
                    union { u64 u[2]; f16x8 v; } c;
                    c.u[0] = expSet ? (a[f].u[0] ^ SIGN_M64) : a[f].u[0];
                    c.u[1] = expSet ? (a[f].u[1] ^ SIGN_M64) : a[f].u[1];
                    const f16x8 Af = c.v;
                    f16x8 Al;
#pragma unroll
                    for (int e = 0; e < 8; ++e)
                        Al[e] = Af[e] * (_Float16)2.44140625e-4f;  // h * 2^-12
                    const f16x8 b0 = *(const f16x8*)(w_hi + (((wv * 8 + f) * 2 + 0) << 9) + lane * 8);
                    const f16x8 b1 = *(const f16x8*)(w_hi + (((wv * 8 + f) * 2 + 1) << 9) + lane * 8);
                    acc[0] = __builtin_amdgcn_mfma_f32_16x16x32_f16(Af, b0, acc[0], 0, 0, 0);
                    acc[0] = __builtin_amdgcn_mfma_f32_16x16x32_f16(Al, blo[f][0], acc[0], 0, 0, 0);
                    acc[1] = __builtin_amdgcn_mfma_f32_16x16x32_f16(Af, b1, acc[1], 0, 0, 0);
                    acc[1] = __builtin_amdgcn_mfma_f32_16x16x32_f16(Al, blo[f][1], acc[1], 0, 0, 0);
                    acc[2] = __builtin_amdgcn_mfma_f32_16x16x32_f16(Af, bh23[f][0], acc[2], 0, 0, 0);
                    acc[2] = __builtin_amdgcn_mfma_f32_16x16x32_f16(Al, blo[f][2], acc[2], 0, 0, 0);
                    acc[3] = __builtin_amdgcn_mfma_f32_16x16x32_f16(Af, bh23[f][1], acc[3], 0, 0, 0);
                    acc[3] = __builtin_amdgcn_mfma_f32_16x16x32_f16(Al, blo[f][3], acc[3], 0, 0, 0);
                    live &= ~(1u << f);
                }
            }
            if (live) {
                // reload rounds are RTT-paced by their own drain; sleep only
                // from the 3rd retry (fabric-spam guard)
                if (++rounds >= 3) __builtin_amdgcn_s_sleep(1);
#pragma unroll
                for (int f = 0; f < 8; ++f) if (live & (1u << f))
                    asm volatile("global_load_dwordx4 %0, %1, off sc1"
                                 : "=v"(a[f].q) : "v"(hb + f * 512) : "memory");
                asm volatile("s_waitcnt vmcnt(0)" ::: "memory");
                __builtin_amdgcn_sched_barrier(0);
            }
        }

        // ---- K-slab partial to LDS scratch (acc already includes lo) ----
#pragma unroll
        for (int nt = 0; nt < 4; ++nt) {
            f16x4 pv;
#pragma unroll
            for (int rr = 0; rr < 4; ++rr)
                pv[rr] = (_Float16)acc[nt][rr];
            *(f16x4*)(sp + (wv * 64 + nt * 16 + lrow) * SP_S + quad * 4) = pv;
        }
        __syncthreads();   // all waves' partials visible in LDS

        // ---- epilogue: 512 threads, one (b, col-pair) each, 8 slabs ----
        {
            float vA = 0.f, vB = 0.f;
#pragma unroll
            for (int s8 = 0; s8 < 8; ++s8) {
                vA += (float)sp[(s8 * 64 + jl    ) * SP_S + ebl];
                vB += (float)sp[(s8 * 64 + jl + 1) * SP_S + ebl];
            }
            if (micro == 0 && (ep_sA >= 0 || ep_sB >= 0)) {
                const float4 x = *(const float4*)(inputs + ((ep_b * T_DIM + t) << 2));
                if (ep_sA >= 0) {
                    const float4 w = *(const float4*)(W_in + (ep_sA << 2));
                    vA += b_in[ep_sA] + x.x * w.x + x.y * w.y + x.z * w.z + x.w * w.w;
                }
                if (ep_sB >= 0) {
                    const float4 w = *(const float4*)(W_in + (ep_sB << 2));
                    vB += b_in[ep_sB] + x.x * w.x + x.y * w.y + x.z * w.z + x.w * w.w;
                }
            }
            union { _Float16 h[2]; unsigned u; } pk;
            pk.h[0] = (_Float16)fmaxf(vA, 0.0f);
            pk.h[1] = (_Float16)fmaxf(vB, 0.0f);
            // parity of h_{step+1}: step+1 even -> sign SET (h>=0, OR sets)
            const unsigned pr = pk.u | ((step & 1) ? SIGN_M32 : 0u);
            // MALL-visible ring store FIRST; 512 lanes = 2 KB contiguous
            __hip_atomic_store((unsigned*)(hnxt + ep_off), pr,
                               __ATOMIC_RELAXED, __HIP_MEMORY_SCOPE_AGENT);
            if (micro == 3) {
                if (ep_uA >= 0) hc[(t * NOUT + ep_uA) * B_DIM + ep_b] = pk.h[0];
                if (ep_uB >= 0) hc[(t * NOUT + ep_uB) * B_DIM + ep_b] = pk.h[1];
            }
        }
        __syncthreads();   // phase alignment + sp WAR (single buffer)

        slot_r = (slot_r + 1 == RING) ? 0 : slot_r + 1;
        slot_w = (slot_w + 1 == RING) ? 0 : slot_w + 1;
    }
}

// ---------------- final readout: out[b][t][o] = hc[t][:][b] . W_out[o][:] + b_out ----

__global__ __launch_bounds__(128)
void k_readout(float* __restrict__ out, const _Float16* __restrict__ hc,
               const float* __restrict__ W_out, const float* __restrict__ b_out) {
    __shared__ _Float16 sh[NOUT * B_DIM];
    const int t = blockIdx.x, tid = threadIdx.x;
    const unsigned int* src = (const unsigned int*)(hc + (size_t)t * NOUT * B_DIM);
    for (int i = tid; i < NOUT * B_DIM / 2; i += 128)
        ((unsigned int*)sh)[i] = src[i];
    __syncthreads();
    const int o = tid >> 6, b = tid & 63;
    float acc = b_out[o];
#pragma unroll 8
    for (int u = 0; u < NOUT; ++u)
        acc += (float)sh[u * B_DIM + b] * W_out[o * NOUT + u];
    out[(b * T_DIM + t) * 2 + o] = acc;
}

// ---------------- host launch ----------------

extern "C" void kernel_launch(void* const* d_in, const int* in_sizes, int n_in,
                              void* d_out, int out_size, void* d_ws, size_t ws_size,
                              hipStream_t stream) {
    const float* inputs = (const float*)d_in[0];
    const float* W_rec  = (const float*)d_in[1];
    const float* W_in   = (const float*)d_in[2];
    const float* b_in   = (const float*)d_in[3];
    const float* W_out  = (const float*)d_in[4];
    const float* b_out  = (const float*)d_in[5];
    const int*   sidx   = (const int*)d_in[6];
    const int*   oidx   = (const int*)d_in[7];

    // ws: ring 786,432 + hc 2,097,152 + inv 16,384 + flags 512 = 2,900,480 B
    char* ws = (char*)d_ws;
    _Float16* ring     = (_Float16*)ws;
    _Float16* hc       = (_Float16*)(ws + 786432);
    int*      inv_sens = (int*)(ws + 786432 + 2097152);
    int*      inv_out  = inv_sens + N_DIM;
    u16*      flags    = (u16*)(inv_out + N_DIM);

    // ring fill: 3*131072/8 = 49,152 uint4 -> 192 blocks x 256
    k_init<<<192, 256, 0, stream>>>((uint4*)ring, inv_sens, inv_out, (u64*)flags);
    k_inv_scatter<<<1, 256, 0, stream>>>(inv_sens, inv_out, sidx, oidx);

    (void)hipFuncSetAttribute((const void*)rnn_main,
                              hipFuncAttributeMaxDynamicSharedMemorySize, SMEM_MAIN);

    rnn_main<<<NWG, THREADS, SMEM_MAIN, stream>>>(
        W_rec, inputs, W_in, b_in, inv_sens, inv_out, ring, hc, flags);

    k_readout<<<T_DIM, 128, 0, stream>>>((float*)d_out, hc, W_out, b_out);
}

// Round 9
// 1322.924 us; speedup vs baseline: 1.7179x; 1.7179x over previous
//
#include <hip/hip_runtime.h>

// ---------------------------------------------------------------------------
// Recurrent ReLU net on MI355X — parity-only dataflow, RING=3, v27.
//   v26 post-mortem (2.27 ms): CW=64/NWG=128 falsified the "exchange is
//   MALL-BW-floored" theory — halving volume nearly DOUBLED the step.
//   Exchange is latency/jitter-bound; doubling per-WG compute slowed
//   producers' stores and raised the stale-first-observation rate (FETCH
//   +5 MB). CW=64 is dead. Reverted to v23 (1.284 ms verified).
//   v27 = v23 + DELAYED PAYLOAD ISSUE (cheap discriminating probe):
//   phase-aligned WGs issue loads ~100-200cy after producers issue stores;
//   store visibility ~600cy but load one-way ~350cy -> the load is often
//   serviced JUST BEFORE the store lands (stale by ~200cy) -> full reload
//   RTT (~900cy). Fix: delay load issue ~300cy using work that must happen
//   anyway — the 16 ds_read_b128 bh reads move BEFORE the payload issue,
//   plus s_sleep(2) (~128cy). Load service then lands after visibility ->
//   first observation fresh, saving (reload RTT - delay) ~500cy/step.
//     Branch A (stale-dominated): ~1150-1220 us, MfmaUtil ~20.
//     Branch B (latency floor): +25-70 us -> roofline write-up next.
//   Lessons kept (verified): joint drain only (v24); both barriers
//   (v20/v22); sc1 only (v22); conditional reload sleep + coalesced ring
//   store (v23); store-ack drain is free (v25 neutral).
//   Carried design (verified r16/v19/v21/v23):
//     - 256 persistent WGs: plane = wg&3 (16 batch rows), cg = wg>>2 (32 cols)
//     - h ring: 3 slots, fp16 MFMA-A-fragment layout, sc1 (MALL) traffic
//     - sign-parity freshness: even steps store -h (sign SET), odd +h;
//       RING=3 (odd) flips parity on slot reuse -> stale never validates
//     - W: hi fp16 in LDS (128 KB), lo (x4096 residual) in VGPRs
//     - 512-thread epilogue, coalesced store map, W_in/b_in hoisted
// ---------------------------------------------------------------------------

#define N_DIM   2048
#define B_DIM   64
#define T_DIM   128
#define NSENS   256
#define NOUT    128
#define NSTEP   512

#define NWG     256
#define THREADS 512
#define CW      32
#define RING    3
#define SLOT_F16 (B_DIM * N_DIM)       // 131072 f16 = 256 KB per slot
#define SP_S    20
#define SP_HALF (256 * SP_S)
#define LDS_W_F16 (CW * N_DIM)         // 128 KB hi
#define SMEM_MAIN (LDS_W_F16 * 2 + 2 * SP_HALF * 2)   // 151,552 B

typedef _Float16 f16x8 __attribute__((ext_vector_type(8)));
typedef _Float16 f16x4 __attribute__((ext_vector_type(4)));
typedef float    f32x4 __attribute__((ext_vector_type(4)));
typedef unsigned long long u64;
typedef unsigned short u16;

#define SIGN_M32 0x80008000u
#define SIGN_M64 0x8000800080008000ULL

union V16 { uint4 q; u64 u[2]; };

// ---------------- setup kernels ----------------

// slot 0 holds h_0 = -0 (sign SET, valid for even step 0).
// slot 1 first read at s=1 (expect CLEAR) -> init SET (invalid).
// slot 2 first read at s=2 (expect SET)  -> init CLEAR (invalid).
__global__ void k_init(uint4* __restrict__ ring, int* __restrict__ inv_sens,
                       int* __restrict__ inv_out, u64* __restrict__ flags) {
    const int i = blockIdx.x * blockDim.x + threadIdx.x;   // 49152 threads
    const int slot = i / (SLOT_F16 / 8);
    if (slot < RING) {
        const unsigned pat = (slot == 0 || (slot & 1)) ? SIGN_M32 : 0u;
        ring[i] = make_uint4(pat, pat, pat, pat);
    }
    if (i < N_DIM) { inv_sens[i] = -1; inv_out[i] = -1; }
    if (i < 64) flags[i] = 0ull;       // unused by v27 main; kept harmless
}

__global__ void k_inv_scatter(int* inv_sens, int* inv_out,
                              const int* sidx, const int* oidx) {
    int i = threadIdx.x;
    if (i < NSENS) inv_sens[sidx[i]] = i;
    if (i < NOUT)  inv_out[oidx[i]] = i;
}

// ---------------- main persistent kernel ----------------
// slot layout: fp16 MFMA A-fragment order.
//   elem (b, j): f16 offset = ((b>>4)*64 + (j>>5))*512 + (((j>>3)&3)*16 + (b&15))*8 + (j&7)
// Fragment (pl, kt) = 1 KB, produced by WG (pl, cg=kt).
// Wave A-load: ONE dense dwordx4 sc1 per fragment (16 B/lane contiguous).
// v23 store map: thread (wv, l=lane&31) owns fragment dword d = wv*32+l  =>
//   ebl = (wv&1)*8 + (l>>2),  ejp = (wv>>1)*4 + (l&3)   (bijective, coalesced)

__global__ __launch_bounds__(THREADS, 2)
void rnn_main(const float* __restrict__ W_rec, const float* __restrict__ inputs,
              const float* __restrict__ W_in, const float* __restrict__ b_in,
              const int* __restrict__ inv_sens, const int* __restrict__ inv_out,
              _Float16* __restrict__ ring, _Float16* __restrict__ hc,
              u16* __restrict__ flags /* unused in v27 */)
{
    extern __shared__ _Float16 smem[];
    _Float16* w_hi = smem;                  // [128 blocks][512]  (kt_local*2+nt major)
    _Float16* sp   = smem + LDS_W_F16;      // [2][256][SP_S]

    const int tid   = threadIdx.x;
    const int wg    = blockIdx.x;
    const int pl    = wg & 3;        // plane: batch rows pl*16..+15
    const int cg    = wg >> 2;       // col group: cols cg*32..+31 (k-tile cg)
    const int jbase = cg * CW;

    const int lane = tid & 63;
    const int wv   = tid >> 6;       // wave = K-slab (k-tiles wv*8..wv*8+7)
    const int lrow = lane & 15;
    const int quad = lane >> 4;
    (void)flags;

    // ---- stage W: hi -> LDS, lo (x4096 residual) -> VGPRs ----
    f16x8 blo[8][2];
#pragma unroll
    for (int nt = 0; nt < 2; ++nt) {
        const float* wr = W_rec + (size_t)(jbase + nt * 16 + lrow) * N_DIM
                        + wv * 256 + quad * 8;
#pragma unroll
        for (int ks = 0; ks < 8; ++ks) {
            const float4 wa = ((const float4*)(wr + ks * 32))[0];
            const float4 wb = ((const float4*)(wr + ks * 32))[1];
            const float w8[8] = {wa.x, wa.y, wa.z, wa.w, wb.x, wb.y, wb.z, wb.w};
            f16x8 hi8;
#pragma unroll
            for (int e = 0; e < 8; ++e) {
                const _Float16 hi = (_Float16)w8[e];
                hi8[e] = hi;
                blo[ks][nt][e] = (_Float16)((w8[e] - (float)hi) * 4096.0f);
            }
            *(f16x8*)(w_hi + ((((wv * 8 + ks) * 2 + nt)) << 9) + lane * 8) = hi8;
        }
    }

    // ---- epilogue constants: coalesced-store mapping (see header) ----
    const int l32   = lane & 31;
    const int ebl   = ((wv & 1) << 3) + (l32 >> 2);   // local batch row 0..15
    const int ejp   = ((wv >> 1) << 2) + (l32 & 3);   // col pair index 0..15
    const int ehalf = lane >> 5;                      // slab half
    const int ep_b  = pl * 16 + ebl;                  // global batch row
    const int ej    = jbase + ejp * 2;                // global col, even
    const int ep_sA = inv_sens[ej], ep_sB = inv_sens[ej + 1];
    const int ep_uA = inv_out[ej],  ep_uB = inv_out[ej + 1];
    // fragment dword d = wv*32 + l32 -> f16 offset = 2*d (contiguous per wave)
    const int ep_off = ((pl * 64 + cg) << 9) + ((wv * 32 + l32) << 1);

    // ---- loop-invariant injection weights -> registers ----
    float4 wA = {0.f, 0.f, 0.f, 0.f}, wB = {0.f, 0.f, 0.f, 0.f};
    float  bA = 0.f, bB = 0.f;
    if (ep_sA >= 0) { wA = *(const float4*)(W_in + (ep_sA << 2)); bA = b_in[ep_sA]; }
    if (ep_sB >= 0) { wB = *(const float4*)(W_in + (ep_sB << 2)); bB = b_in[ep_sB]; }
    __syncthreads();

    int slot_r = 0, slot_w = 1;

    for (int step = 0; step < NSTEP; ++step) {
        const int t = step >> 2, micro = step & 3;
        const bool expSet = (step & 1) == 0;     // parity of h_step
        const _Float16* __restrict__ hcur = ring + (size_t)slot_r * SLOT_F16;
        _Float16* __restrict__       hnxt = ring + (size_t)slot_w * SLOT_F16;

        // ---- x prefetch (micro==0 steps): hides under the consume phase ----
        float4 x = {0.f, 0.f, 0.f, 0.f};
        if (micro == 0) x = *(const float4*)(inputs + ((ep_b * T_DIM + t) << 2));

        // ---- hi fragments from LDS FIRST: this (plus a short sleep) delays
        // the payload-load issue ~300cy so the load is serviced AFTER the
        // producers' stores become MALL-visible -> fresh first observation
        // instead of a thin-margin stale + full reload RTT. ----
        f16x8 bh[8][2];
#pragma unroll
        for (int ks = 0; ks < 8; ++ks)
#pragma unroll
            for (int nt = 0; nt < 2; ++nt)
                bh[ks][nt] = *(const f16x8*)(w_hi + (((wv * 8 + ks) * 2 + nt) << 9) + lane * 8);
        __builtin_amdgcn_s_sleep(2);   // ~128cy extra margin (tunable)

        // ---- issue 8 payload fragments (no drain yet) ----
        const _Float16* hb = hcur + ((pl * 64 + wv * 8) << 9) + lane * 8;
        V16 a[8];
        asm volatile(
            "global_load_dwordx4 %0, %8, off sc1\n\t"
            "global_load_dwordx4 %1, %9, off sc1\n\t"
            "global_load_dwordx4 %2, %10, off sc1\n\t"
            "global_load_dwordx4 %3, %11, off sc1\n\t"
            "global_load_dwordx4 %4, %12, off sc1\n\t"
            "global_load_dwordx4 %5, %13, off sc1\n\t"
            "global_load_dwordx4 %6, %14, off sc1\n\t"
            "global_load_dwordx4 %7, %15, off sc1"
            : "=v"(a[0].q), "=v"(a[1].q), "=v"(a[2].q), "=v"(a[3].q),
              "=v"(a[4].q), "=v"(a[5].q), "=v"(a[6].q), "=v"(a[7].q)
            : "v"(hb),        "v"(hb + 512),  "v"(hb + 1024), "v"(hb + 1536),
              "v"(hb + 2048), "v"(hb + 2560), "v"(hb + 3072), "v"(hb + 3584)
            : "memory");

        f32x4 acch[2], accl[2];
#pragma unroll
        for (int nt = 0; nt < 2; ++nt) {
            acch[nt] = (f32x4){0.f, 0.f, 0.f, 0.f};
            accl[nt] = (f32x4){0.f, 0.f, 0.f, 0.f};
        }

        // ---- LATE joint drain, then parity-driven consume (v19/v21/v23) ----
        asm volatile("s_waitcnt vmcnt(0)" ::: "memory");
        __builtin_amdgcn_sched_barrier(0);   // rule #18: pin parity VALU after drain

        unsigned live = 0xFFu;
        int rounds = 0;
        while (live) {
#pragma unroll
            for (int f = 0; f < 8; ++f) if (live & (1u << f)) {
                const u64 band = a[f].u[0] & a[f].u[1];
                const u64 bor  = a[f].u[0] | a[f].u[1];
                const bool ok = expSet ? ((band & SIGN_M64) == SIGN_M64)
                                       : ((bor  & SIGN_M64) == 0);
                if (__all((int)ok)) {
                    union { u64 u[2]; f16x8 v; } c;
                    c.u[0] = expSet ? (a[f].u[0] ^ SIGN_M64) : a[f].u[0];
                    c.u[1] = expSet ? (a[f].u[1] ^ SIGN_M64) : a[f].u[1];
                    const f16x8 Af = c.v;
                    acch[0] = __builtin_amdgcn_mfma_f32_16x16x32_f16(Af, bh[f][0], acch[0], 0, 0, 0);
                    accl[0] = __builtin_amdgcn_mfma_f32_16x16x32_f16(Af, blo[f][0], accl[0], 0, 0, 0);
                    acch[1] = __builtin_amdgcn_mfma_f32_16x16x32_f16(Af, bh[f][1], acch[1], 0, 0, 0);
                    accl[1] = __builtin_amdgcn_mfma_f32_16x16x32_f16(Af, blo[f][1], accl[1], 0, 0, 0);
                    live &= ~(1u << f);
                }
            }
            if (live) {
                // reload rounds are RTT-paced by their own drain; sleep only
                // from the 3rd retry (fabric-spam guard for long waits)
                if (++rounds >= 3) __builtin_amdgcn_s_sleep(1);
#pragma unroll
                for (int f = 0; f < 8; ++f) if (live & (1u << f))
                    asm volatile("global_load_dwordx4 %0, %1, off sc1"
                                 : "=v"(a[f].q) : "v"(hb + f * 512) : "memory");
                asm volatile("s_waitcnt vmcnt(0)" ::: "memory");
                __builtin_amdgcn_sched_barrier(0);
            }
        }

        // ---- K-slab partial (hi + lo/4096) to LDS scratch ----
        _Float16* sph = sp + (step & 1) * SP_HALF;
#pragma unroll
        for (int nt = 0; nt < 2; ++nt) {
            f16x4 pv;
#pragma unroll
            for (int r = 0; r < 4; ++r)
                pv[r] = (_Float16)(acch[nt][r] + accl[nt][r] * 2.44140625e-4f);
            *(f16x4*)(sph + (wv * 32 + nt * 16 + lrow) * SP_S + quad * 4) = pv;
        }
        __syncthreads();   // all waves' partials in LDS

        // ---- epilogue: 512 threads, 4 slabs x 2 cols each, butterfly ----
        {
            float vA = 0.f, vB = 0.f;
#pragma unroll
            for (int s = 0; s < 4; ++s) {
                const int s8 = ehalf * 4 + s;
                vA += (float)sph[(s8 * 32 + ejp * 2    ) * SP_S + ebl];
                vB += (float)sph[(s8 * 32 + ejp * 2 + 1) * SP_S + ebl];
            }
            vA += __shfl_xor(vA, 32, 64);
            vB += __shfl_xor(vB, 32, 64);
            if (lane < 32) {
                if (micro == 0) {
                    vA += bA + x.x * wA.x + x.y * wA.y + x.z * wA.z + x.w * wA.w;
                    vB += bB + x.x * wB.x + x.y * wB.y + x.z * wB.z + x.w * wB.w;
                }
                union { _Float16 h[2]; unsigned u; } pk;
                pk.h[0] = (_Float16)fmaxf(vA, 0.0f);
                pk.h[1] = (_Float16)fmaxf(vB, 0.0f);
                // parity of h_{step+1}: step+1 even -> sign SET (h>=0, OR sets)
                const unsigned pr = pk.u | ((step & 1) ? SIGN_M32 : 0u);
                // MALL-visible ring store FIRST; 32 lanes = 128 B contiguous
                __hip_atomic_store((unsigned*)(hnxt + ep_off), pr,
                                   __ATOMIC_RELAXED, __HIP_MEMORY_SCOPE_AGENT);
                if (micro == 3) {
                    if (ep_uA >= 0) hc[(t * NOUT + ep_uA) * B_DIM + ep_b] = pk.h[0];
                    if (ep_uB >= 0) hc[(t * NOUT + ep_uB) * B_DIM + ep_b] = pk.h[1];
                }
            }
        }
        __syncthreads();   // keep waves phase-aligned (polling must start LATE)

        slot_r = (slot_r + 1 == RING) ? 0 : slot_r + 1;
        slot_w = (slot_w + 1 == RING) ? 0 : slot_w + 1;
    }
}

// ---------------- final readout: out[b][t][o] = hc[t][:][b] . W_out[o][:] + b_out ----

__global__ __launch_bounds__(128)
void k_readout(float* __restrict__ out, const _Float16* __restrict__ hc,
               const float* __restrict__ W_out, const float* __restrict__ b_out) {
    __shared__ _Float16 sh[NOUT * B_DIM];
    const int t = blockIdx.x, tid = threadIdx.x;
    const unsigned int* src = (const unsigned int*)(hc + (size_t)t * NOUT * B_DIM);
    for (int i = tid; i < NOUT * B_DIM / 2; i += 128)
        ((unsigned int*)sh)[i] = src[i];
    __syncthreads();
    const int o = tid >> 6, b = tid & 63;
    float acc = b_out[o];
#pragma unroll 8
    for (int u = 0; u < NOUT; ++u)
        acc += (float)sh[u * B_DIM + b] * W_out[o * NOUT + u];
    out[(b * T_DIM + t) * 2 + o] = acc;
}

// ---------------- host launch ----------------

extern "C" void kernel_launch(void* const* d_in, const int* in_sizes, int n_in,
                              void* d_out, int out_size, void* d_ws, size_t ws_size,
                              hipStream_t stream) {
    const float* inputs = (const float*)d_in[0];
    const float* W_rec  = (const float*)d_in[1];
    const float* W_in   = (const float*)d_in[2];
    const float* b_in   = (const float*)d_in[3];
    const float* W_out  = (const float*)d_in[4];
    const float* b_out  = (const float*)d_in[5];
    const int*   sidx   = (const int*)d_in[6];
    const int*   oidx   = (const int*)d_in[7];

    // ws: ring 786,432 + hc 2,097,152 + inv 16,384 + flags 512 = 2,900,480 B
    char* ws = (char*)d_ws;
    _Float16* ring     = (_Float16*)ws;
    _Float16* hc       = (_Float16*)(ws + 786432);
    int*      inv_sens = (int*)(ws + 786432 + 2097152);
    int*      inv_out  = inv_sens + N_DIM;
    u16*      flags    = (u16*)(inv_out + N_DIM);

    // ring fill: 3*131072/8 = 49,152 uint4 -> 192 blocks x 256
    k_init<<<192, 256, 0, stream>>>((uint4*)ring, inv_sens, inv_out, (u64*)flags);
    k_inv_scatter<<<1, 256, 0, stream>>>(inv_sens, inv_out, sidx, oidx);

    (void)hipFuncSetAttribute((const void*)rnn_main,
                              hipFuncAttributeMaxDynamicSharedMemorySize, SMEM_MAIN);

    rnn_main<<<NWG, THREADS, SMEM_MAIN, stream>>>(
        W_rec, inputs, W_in, b_in, inv_sens, inv_out, ring, hc, flags);

    k_readout<<<T_DIM, 128, 0, stream>>>((float*)d_out, hc, W_out, b_out);
}

// Round 10
// 1283.945 us; speedup vs baseline: 1.7700x; 1.0304x over previous
//
#include <hip/hip_runtime.h>

// ---------------------------------------------------------------------------
// Recurrent ReLU net on MI355X — parity-only dataflow, RING=3, v28.
//   EXACT REVERT to v23 (1.284 ms verified — session best). v27's delayed-
//   issue probe confirmed Branch B: first payload observations are already
//   FRESH; the consume phase sits at irreducible MALL visibility+RTT, not a
//   stale-retry penalty. All structural levers now resolved:
//     v19 flag removal (-442us, real) / v21+v23 epilogue chain (-247us,
//     real) / v20+v24 early checking (falsified 2x) / v22 sc0 local polling
//     (falsified: L2 never freshens) / v26 volume halving (falsified: not
//     BW-bound) / v27 issue-delay (falsified: already fresh).
//   Remaining ~6100cy/step = load RTT (~900) + MFMA+validate (~500) +
//   reduce/epilogue (~700) + store visibility (~600) + plane-wide
//   max-of-8-producers jitter coupling absorbing the remainder — a
//   serial-dependence latency floor, not a memory/compute roofline.
//   Structural escapes hit walls: full-K-per-wave needs 256 VGPRs or
//   +128KB LDS for W-lo; relay/broadcast dies on v22 L2-staleness;
//   finer planes die on MFMA M=16; coarser CW dies on LDS capacity.
//   Design (verified r16/v19/v21/v23):
//     - 256 persistent WGs: plane = wg&3 (16 batch rows), cg = wg>>2 (32 cols)
//     - h ring: 3 slots, fp16 MFMA-A-fragment layout, sc1 (MALL) traffic
//     - sign-parity freshness: even steps store -h (sign SET), odd +h;
//       RING=3 (odd) flips parity on slot reuse -> stale never validates
//     - LATE joint drain + parity consume; reload rounds RTT-paced,
//       conditional sleep from 3rd retry
//     - W: hi fp16 in LDS (128 KB), lo (x4096 residual) in VGPRs
//     - 512-thread epilogue, butterfly reduce, coalesced 128B ring store
//       (bank-conflict-free), W_in/b_in hoisted, x prefetched
// ---------------------------------------------------------------------------

#define N_DIM   2048
#define B_DIM   64
#define T_DIM   128
#define NSENS   256
#define NOUT    128
#define NSTEP   512

#define NWG     256
#define THREADS 512
#define CW      32
#define RING    3
#define SLOT_F16 (B_DIM * N_DIM)       // 131072 f16 = 256 KB per slot
#define SP_S    20
#define SP_HALF (256 * SP_S)
#define LDS_W_F16 (CW * N_DIM)         // 128 KB hi
#define SMEM_MAIN (LDS_W_F16 * 2 + 2 * SP_HALF * 2)   // 151,552 B

typedef _Float16 f16x8 __attribute__((ext_vector_type(8)));
typedef _Float16 f16x4 __attribute__((ext_vector_type(4)));
typedef float    f32x4 __attribute__((ext_vector_type(4)));
typedef unsigned long long u64;
typedef unsigned short u16;

#define SIGN_M32 0x80008000u
#define SIGN_M64 0x8000800080008000ULL

union V16 { uint4 q; u64 u[2]; };

// ---------------- setup kernels ----------------

// slot 0 holds h_0 = -0 (sign SET, valid for even step 0).
// slot 1 first read at s=1 (expect CLEAR) -> init SET (invalid).
// slot 2 first read at s=2 (expect SET)  -> init CLEAR (invalid).
__global__ void k_init(uint4* __restrict__ ring, int* __restrict__ inv_sens,
                       int* __restrict__ inv_out, u64* __restrict__ flags) {
    const int i = blockIdx.x * blockDim.x + threadIdx.x;   // 49152 threads
    const int slot = i / (SLOT_F16 / 8);
    if (slot < RING) {
        const unsigned pat = (slot == 0 || (slot & 1)) ? SIGN_M32 : 0u;
        ring[i] = make_uint4(pat, pat, pat, pat);
    }
    if (i < N_DIM) { inv_sens[i] = -1; inv_out[i] = -1; }
    if (i < 64) flags[i] = 0ull;       // unused by v28 main; kept harmless
}

__global__ void k_inv_scatter(int* inv_sens, int* inv_out,
                              const int* sidx, const int* oidx) {
    int i = threadIdx.x;
    if (i < NSENS) inv_sens[sidx[i]] = i;
    if (i < NOUT)  inv_out[oidx[i]] = i;
}

// ---------------- main persistent kernel ----------------
// slot layout: fp16 MFMA A-fragment order.
//   elem (b, j): f16 offset = ((b>>4)*64 + (j>>5))*512 + (((j>>3)&3)*16 + (b&15))*8 + (j&7)
// Fragment (pl, kt) = 1 KB, produced by WG (pl, cg=kt).
// Wave A-load: ONE dense dwordx4 sc1 per fragment (16 B/lane contiguous).
// v23 store map: thread (wv, l=lane&31) owns fragment dword d = wv*32+l  =>
//   ebl = (wv&1)*8 + (l>>2),  ejp = (wv>>1)*4 + (l&3)   (bijective, coalesced)

__global__ __launch_bounds__(THREADS, 2)
void rnn_main(const float* __restrict__ W_rec, const float* __restrict__ inputs,
              const float* __restrict__ W_in, const float* __restrict__ b_in,
              const int* __restrict__ inv_sens, const int* __restrict__ inv_out,
              _Float16* __restrict__ ring, _Float16* __restrict__ hc,
              u16* __restrict__ flags /* unused in v28 */)
{
    extern __shared__ _Float16 smem[];
    _Float16* w_hi = smem;                  // [128 blocks][512]  (kt_local*2+nt major)
    _Float16* sp   = smem + LDS_W_F16;      // [2][256][SP_S]

    const int tid   = threadIdx.x;
    const int wg    = blockIdx.x;
    const int pl    = wg & 3;        // plane: batch rows pl*16..+15
    const int cg    = wg >> 2;       // col group: cols cg*32..+31 (k-tile cg)
    const int jbase = cg * CW;

    const int lane = tid & 63;
    const int wv   = tid >> 6;       // wave = K-slab (k-tiles wv*8..wv*8+7)
    const int lrow = lane & 15;
    const int quad = lane >> 4;
    (void)flags;

    // ---- stage W: hi -> LDS, lo (x4096 residual) -> VGPRs ----
    f16x8 blo[8][2];
#pragma unroll
    for (int nt = 0; nt < 2; ++nt) {
        const float* wr = W_rec + (size_t)(jbase + nt * 16 + lrow) * N_DIM
                        + wv * 256 + quad * 8;
#pragma unroll
        for (int ks = 0; ks < 8; ++ks) {
            const float4 wa = ((const float4*)(wr + ks * 32))[0];
            const float4 wb = ((const float4*)(wr + ks * 32))[1];
            const float w8[8] = {wa.x, wa.y, wa.z, wa.w, wb.x, wb.y, wb.z, wb.w};
            f16x8 hi8;
#pragma unroll
            for (int e = 0; e < 8; ++e) {
                const _Float16 hi = (_Float16)w8[e];
                hi8[e] = hi;
                blo[ks][nt][e] = (_Float16)((w8[e] - (float)hi) * 4096.0f);
            }
            *(f16x8*)(w_hi + ((((wv * 8 + ks) * 2 + nt)) << 9) + lane * 8) = hi8;
        }
    }

    // ---- epilogue constants: coalesced-store mapping (see header) ----
    const int l32   = lane & 31;
    const int ebl   = ((wv & 1) << 3) + (l32 >> 2);   // local batch row 0..15
    const int ejp   = ((wv >> 1) << 2) + (l32 & 3);   // col pair index 0..15
    const int ehalf = lane >> 5;                      // slab half
    const int ep_b  = pl * 16 + ebl;                  // global batch row
    const int ej    = jbase + ejp * 2;                // global col, even
    const int ep_sA = inv_sens[ej], ep_sB = inv_sens[ej + 1];
    const int ep_uA = inv_out[ej],  ep_uB = inv_out[ej + 1];
    // fragment dword d = wv*32 + l32 -> f16 offset = 2*d (contiguous per wave)
    const int ep_off = ((pl * 64 + cg) << 9) + ((wv * 32 + l32) << 1);

    // ---- loop-invariant injection weights -> registers ----
    float4 wA = {0.f, 0.f, 0.f, 0.f}, wB = {0.f, 0.f, 0.f, 0.f};
    float  bA = 0.f, bB = 0.f;
    if (ep_sA >= 0) { wA = *(const float4*)(W_in + (ep_sA << 2)); bA = b_in[ep_sA]; }
    if (ep_sB >= 0) { wB = *(const float4*)(W_in + (ep_sB << 2)); bB = b_in[ep_sB]; }
    __syncthreads();

    int slot_r = 0, slot_w = 1;

    for (int step = 0; step < NSTEP; ++step) {
        const int t = step >> 2, micro = step & 3;
        const bool expSet = (step & 1) == 0;     // parity of h_step
        const _Float16* __restrict__ hcur = ring + (size_t)slot_r * SLOT_F16;
        _Float16* __restrict__       hnxt = ring + (size_t)slot_w * SLOT_F16;

        // ---- x prefetch (micro==0 steps): hides under the consume phase ----
        float4 x = {0.f, 0.f, 0.f, 0.f};
        if (micro == 0) x = *(const float4*)(inputs + ((ep_b * T_DIM + t) << 2));

        // ---- issue 8 payload fragments (no drain yet) ----
        const _Float16* hb = hcur + ((pl * 64 + wv * 8) << 9) + lane * 8;
        V16 a[8];
        asm volatile(
            "global_load_dwordx4 %0, %8, off sc1\n\t"
            "global_load_dwordx4 %1, %9, off sc1\n\t"
            "global_load_dwordx4 %2, %10, off sc1\n\t"
            "global_load_dwordx4 %3, %11, off sc1\n\t"
            "global_load_dwordx4 %4, %12, off sc1\n\t"
            "global_load_dwordx4 %5, %13, off sc1\n\t"
            "global_load_dwordx4 %6, %14, off sc1\n\t"
            "global_load_dwordx4 %7, %15, off sc1"
            : "=v"(a[0].q), "=v"(a[1].q), "=v"(a[2].q), "=v"(a[3].q),
              "=v"(a[4].q), "=v"(a[5].q), "=v"(a[6].q), "=v"(a[7].q)
            : "v"(hb),        "v"(hb + 512),  "v"(hb + 1024), "v"(hb + 1536),
              "v"(hb + 2048), "v"(hb + 2560), "v"(hb + 3072), "v"(hb + 3584)
            : "memory");

        // ---- hi fragments from LDS (overlaps payload flight) ----
        f16x8 bh[8][2];
#pragma unroll
        for (int ks = 0; ks < 8; ++ks)
#pragma unroll
            for (int nt = 0; nt < 2; ++nt)
                bh[ks][nt] = *(const f16x8*)(w_hi + (((wv * 8 + ks) * 2 + nt) << 9) + lane * 8);

        f32x4 acch[2], accl[2];
#pragma unroll
        for (int nt = 0; nt < 2; ++nt) {
            acch[nt] = (f32x4){0.f, 0.f, 0.f, 0.f};
            accl[nt] = (f32x4){0.f, 0.f, 0.f, 0.f};
        }

        // ---- LATE joint drain, then parity-driven consume (v19/v21/v23).
        // Checking late maximizes first-observation freshness. ----
        asm volatile("s_waitcnt vmcnt(0)" ::: "memory");
        __builtin_amdgcn_sched_barrier(0);   // rule #18: pin parity VALU after drain

        unsigned live = 0xFFu;
        int rounds = 0;
        while (live) {
#pragma unroll
            for (int f = 0; f < 8; ++f) if (live & (1u << f)) {
                const u64 band = a[f].u[0] & a[f].u[1];
                const u64 bor  = a[f].u[0] | a[f].u[1];
                const bool ok = expSet ? ((band & SIGN_M64) == SIGN_M64)
                                       : ((bor  & SIGN_M64) == 0);
                if (__all((int)ok)) {
                    union { u64 u[2]; f16x8 v; } c;
                    c.u[0] = expSet ? (a[f].u[0] ^ SIGN_M64) : a[f].u[0];
                    c.u[1] = expSet ? (a[f].u[1] ^ SIGN_M64) : a[f].u[1];
                    const f16x8 Af = c.v;
                    acch[0] = __builtin_amdgcn_mfma_f32_16x16x32_f16(Af, bh[f][0], acch[0], 0, 0, 0);
                    accl[0] = __builtin_amdgcn_mfma_f32_16x16x32_f16(Af, blo[f][0], accl[0], 0, 0, 0);
                    acch[1] = __builtin_amdgcn_mfma_f32_16x16x32_f16(Af, bh[f][1], acch[1], 0, 0, 0);
                    accl[1] = __builtin_amdgcn_mfma_f32_16x16x32_f16(Af, blo[f][1], accl[1], 0, 0, 0);
                    live &= ~(1u << f);
                }
            }
            if (live) {
                // reload rounds are RTT-paced by their own drain; sleep only
                // from the 3rd retry (fabric-spam guard for long waits)
                if (++rounds >= 3) __builtin_amdgcn_s_sleep(1);
#pragma unroll
                for (int f = 0; f < 8; ++f) if (live & (1u << f))
                    asm volatile("global_load_dwordx4 %0, %1, off sc1"
                                 : "=v"(a[f].q) : "v"(hb + f * 512) : "memory");
                asm volatile("s_waitcnt vmcnt(0)" ::: "memory");
                __builtin_amdgcn_sched_barrier(0);
            }
        }

        // ---- K-slab partial (hi + lo/4096) to LDS scratch ----
        _Float16* sph = sp + (step & 1) * SP_HALF;
#pragma unroll
        for (int nt = 0; nt < 2; ++nt) {
            f16x4 pv;
#pragma unroll
            for (int r = 0; r < 4; ++r)
                pv[r] = (_Float16)(acch[nt][r] + accl[nt][r] * 2.44140625e-4f);
            *(f16x4*)(sph + (wv * 32 + nt * 16 + lrow) * SP_S + quad * 4) = pv;
        }
        __syncthreads();   // all waves' partials in LDS

        // ---- epilogue: 512 threads, 4 slabs x 2 cols each, butterfly ----
        {
            float vA = 0.f, vB = 0.f;
#pragma unroll
            for (int s = 0; s < 4; ++s) {
                const int s8 = ehalf * 4 + s;
                vA += (float)sph[(s8 * 32 + ejp * 2    ) * SP_S + ebl];
                vB += (float)sph[(s8 * 32 + ejp * 2 + 1) * SP_S + ebl];
            }
            vA += __shfl_xor(vA, 32, 64);
            vB += __shfl_xor(vB, 32, 64);
            if (lane < 32) {
                if (micro == 0) {
                    vA += bA + x.x * wA.x + x.y * wA.y + x.z * wA.z + x.w * wA.w;
                    vB += bB + x.x * wB.x + x.y * wB.y + x.z * wB.z + x.w * wB.w;
                }
                union { _Float16 h[2]; unsigned u; } pk;
                pk.h[0] = (_Float16)fmaxf(vA, 0.0f);
                pk.h[1] = (_Float16)fmaxf(vB, 0.0f);
                // parity of h_{step+1}: step+1 even -> sign SET (h>=0, OR sets)
                const unsigned pr = pk.u | ((step & 1) ? SIGN_M32 : 0u);
                // MALL-visible ring store FIRST; 32 lanes = 128 B contiguous
                __hip_atomic_store((unsigned*)(hnxt + ep_off), pr,
                                   __ATOMIC_RELAXED, __HIP_MEMORY_SCOPE_AGENT);
                if (micro == 3) {
                    if (ep_uA >= 0) hc[(t * NOUT + ep_uA) * B_DIM + ep_b] = pk.h[0];
                    if (ep_uB >= 0) hc[(t * NOUT + ep_uB) * B_DIM + ep_b] = pk.h[1];
                }
            }
        }
        __syncthreads();   // keep waves phase-aligned (polling must start LATE)

        slot_r = (slot_r + 1 == RING) ? 0 : slot_r + 1;
        slot_w = (slot_w + 1 == RING) ? 0 : slot_w + 1;
    }
}

// ---------------- final readout: out[b][t][o] = hc[t][:][b] . W_out[o][:] + b_out ----

__global__ __launch_bounds__(128)
void k_readout(float* __restrict__ out, const _Float16* __restrict__ hc,
               const float* __restrict__ W_out, const float* __restrict__ b_out) {
    __shared__ _Float16 sh[NOUT * B_DIM];
    const int t = blockIdx.x, tid = threadIdx.x;
    const unsigned int* src = (const unsigned int*)(hc + (size_t)t * NOUT * B_DIM);
    for (int i = tid; i < NOUT * B_DIM / 2; i += 128)
        ((unsigned int*)sh)[i] = src[i];
    __syncthreads();
    const int o = tid >> 6, b = tid & 63;
    float acc = b_out[o];
#pragma unroll 8
    for (int u = 0; u < NOUT; ++u)
        acc += (float)sh[u * B_DIM + b] * W_out[o * NOUT + u];
    out[(b * T_DIM + t) * 2 + o] = acc;
}

// ---------------- host launch ----------------

extern "C" void kernel_launch(void* const* d_in, const int* in_sizes, int n_in,
                              void* d_out, int out_size, void* d_ws, size_t ws_size,
                              hipStream_t stream) {
    const float* inputs = (const float*)d_in[0];
    const float* W_rec  = (const float*)d_in[1];
    const float* W_in   = (const float*)d_in[2];
    const float* b_in   = (const float*)d_in[3];
    const float* W_out  = (const float*)d_in[4];
    const float* b_out  = (const float*)d_in[5];
    const int*   sidx   = (const int*)d_in[6];
    const int*   oidx   = (const int*)d_in[7];

    // ws: ring 786,432 + hc 2,097,152 + inv 16,384 + flags 512 = 2,900,480 B
    char* ws = (char*)d_ws;
    _Float16* ring     = (_Float16*)ws;
    _Float16* hc       = (_Float16*)(ws + 786432);
    int*      inv_sens = (int*)(ws + 786432 + 2097152);
    int*      inv_out  = inv_sens + N_DIM;
    u16*      flags    = (u16*)(inv_out + N_DIM);

    // ring fill: 3*131072/8 = 49,152 uint4 -> 192 blocks x 256
    k_init<<<192, 256, 0, stream>>>((uint4*)ring, inv_sens, inv_out, (u64*)flags);
    k_inv_scatter<<<1, 256, 0, stream>>>(inv_sens, inv_out, sidx, oidx);

    (void)hipFuncSetAttribute((const void*)rnn_main,
                              hipFuncAttributeMaxDynamicSharedMemorySize, SMEM_MAIN);

    rnn_main<<<NWG, THREADS, SMEM_MAIN, stream>>>(
        W_rec, inputs, W_in, b_in, inv_sens, inv_out, ring, hc, flags);

    k_readout<<<T_DIM, 128, 0, stream>>>((float*)d_out, hc, W_out, b_out);
}